// Round 7
// baseline (187.454 us; speedup 1.0000x reference)
//
#include <hip/hip_runtime.h>
#include <hip/hip_bf16.h>

#define INF 768
#define NSHORT 2000
#define NHEAD 2003

typedef __attribute__((ext_vector_type(8))) short  s16x8;
typedef __attribute__((ext_vector_type(4))) float  f32x4;
typedef __attribute__((ext_vector_type(8))) float  f32x8;

__device__ __forceinline__ float sigf(float z) { return 1.f / (1.f + __expf(-z)); }
__device__ __forceinline__ float softplusf(float z) {
    return fmaxf(z, 0.f) + __logf(1.f + __expf(-fabsf(z)));
}
__device__ __forceinline__ float qreduce16(float v) {
    v += __shfl_xor(v, 1); v += __shfl_xor(v, 2);
    v += __shfl_xor(v, 4); v += __shfl_xor(v, 8);
    return v;
}
__device__ __forceinline__ float wreduce64(float v) {
    v += __shfl_xor(v, 1);  v += __shfl_xor(v, 2);  v += __shfl_xor(v, 4);
    v += __shfl_xor(v, 8);  v += __shfl_xor(v, 16); v += __shfl_xor(v, 32);
    return v;
}
__device__ __forceinline__ short bfc(float x) {
    union { __hip_bfloat16 h; short s; } u; u.h = __float2bfloat16(x); return u.s;
}

// ---- staged MFMA GEMM: fp32 W -> (LDS, fragment order, one barrier) -> MFMA ----
// Block = 256 rows x 64-col stripe, 4 waves x 64 rows. W fragment chunk (j*4+ct)*64+lane
// holds W[col=stripe*64+ct*16+(lane&15)][kbase+j*32+(lane>>4)*8 .. +8).
// A: AF32 ? fp32 x[256,ldA] (cvt in double-buffer) : fragment-linear bf16 (ldA=K32 chunks/tile).
// MODE 0: store z (f32, col<N). MODE 2: grouped-log BCE row-sums -> part[pslot*256+row].
template <int K32, int MODE, int AF32>
__device__ __forceinline__ void core_s(
    const void* __restrict__ Av, int ldA, int kbase,
    const float* __restrict__ W, int Kfull, int N, int stripe,
    short* __restrict__ lds,
    float* __restrict__ outH, int ldH,
    float* __restrict__ part, int pslot,
    const float* __restrict__ rootlogit, int ci)
{
    const int t = threadIdx.x;
    const int wave = t >> 6, lane = t & 63;
    const int quad = lane >> 4, l16 = lane & 15;
    const int rtb = wave * 4;

    // --- stage W stripe into LDS in fragment order (one pass, coalesced lines) ---
    {
        const int ct = t >> 6, l = t & 63;
        int col = stripe * 64 + ct * 16 + (l & 15);
        if (col >= N) col = N - 1;
        const float* src = W + (size_t)col * Kfull + kbase + (l >> 4) * 8;
        short* dst = lds + ((size_t)ct * 64 + l) * 8;
#pragma unroll
        for (int s = 0; s < K32; s++) {
            const f32x8 v = *(const f32x8*)(src + s * 32);
            s16x8 o;
#pragma unroll
            for (int i = 0; i < 8; i++) o[i] = bfc(v[i]);
            *(s16x8*)(dst + (size_t)s * 2048) = o;
        }
    }

    // --- A prologue (j=0), issued before the barrier (independent of LDS) ---
    s16x8 af[2][4];
    const float* axp[4];
    const short* app[4];
    if (AF32) {
#pragma unroll
        for (int rt = 0; rt < 4; rt++) {
            axp[rt] = (const float*)Av + (size_t)((rtb + rt) * 16 + l16) * ldA + kbase + quad * 8;
            const f32x8 v = *(const f32x8*)(axp[rt]);
#pragma unroll
            for (int i = 0; i < 8; i++) af[0][rt][i] = bfc(v[i]);
        }
    } else {
#pragma unroll
        for (int rt = 0; rt < 4; rt++) {
            app[rt] = (const short*)Av + ((size_t)(rtb + rt) * ldA * 64 + lane) * 8;
            af[0][rt] = *(const s16x8*)(app[rt]);
        }
    }

    __syncthreads();

    const short* wbase = lds + (size_t)lane * 8;
    s16x8 wf[2][4];
#pragma unroll
    for (int ct = 0; ct < 4; ct++)
        wf[0][ct] = *(const s16x8*)(wbase + (size_t)ct * 512);

    f32x4 acc[4][4];
#pragma unroll
    for (int rt = 0; rt < 4; rt++)
#pragma unroll
        for (int ct = 0; ct < 4; ct++) acc[rt][ct] = (f32x4){0.f, 0.f, 0.f, 0.f};

#pragma unroll
    for (int j = 0; j < K32; j++) {
        const int b = j & 1, nb = b ^ 1;
        if (j + 1 < K32) {
            if (AF32) {
#pragma unroll
                for (int rt = 0; rt < 4; rt++) {
                    const f32x8 v = *(const f32x8*)(axp[rt] + (size_t)(j + 1) * 32);
#pragma unroll
                    for (int i = 0; i < 8; i++) af[nb][rt][i] = bfc(v[i]);
                }
            } else {
#pragma unroll
                for (int rt = 0; rt < 4; rt++)
                    af[nb][rt] = *(const s16x8*)(app[rt] + (size_t)(j + 1) * 512);
            }
#pragma unroll
            for (int ct = 0; ct < 4; ct++)
                wf[nb][ct] = *(const s16x8*)(wbase + (size_t)(j + 1) * 2048 + ct * 512);
        }
#pragma unroll
        for (int rt = 0; rt < 4; rt++)
#pragma unroll
            for (int ct = 0; ct < 4; ct++)
                acc[rt][ct] = __builtin_amdgcn_mfma_f32_16x16x32_bf16(
                    af[b][rt], wf[b][ct], acc[rt][ct], 0, 0, 0);
    }

    const int col0 = stripe * 64;
    if (MODE == 0) {
#pragma unroll
        for (int rt = 0; rt < 4; rt++)
#pragma unroll
            for (int ct = 0; ct < 4; ct++) {
                const int col = col0 + ct * 16 + l16;
                if (col < N) {
#pragma unroll
                    for (int r = 0; r < 4; r++)
                        outH[(size_t)((rtb + rt) * 16 + quad * 4 + r) * ldH + col] =
                            acc[rt][ct][r];
                }
            }
    } else {
        // sum_ct -log(1-r*sig(z)) = log prod(1+t) - log prod(1+t-r), t=e^-z
#pragma unroll
        for (int rt = 0; rt < 4; rt++) {
#pragma unroll
            for (int r = 0; r < 4; r++) {
                const int row = (rtb + rt) * 16 + quad * 4 + r;
                const float rv = sigf(rootlogit[row * 3 + ci]);
                float pd = 1.f, pn = 1.f;
#pragma unroll
                for (int ct = 0; ct < 4; ct++) {
                    const int col = col0 + ct * 16 + l16;
                    const float tv = fminf(__expf(-acc[rt][ct][r]), 1e6f);
                    const float d = (col < N) ? (1.f + tv) : 1.f;
                    const float n = (col < N) ? (1.f + tv - rv) : 1.f;
                    pd *= d; pn *= n;
                }
                float s = __logf(pd) - __logf(pn);
                s = qreduce16(s);
                if (l16 == 0) part[(size_t)pslot * 256 + row] = s;
            }
        }
    }
}

// split-K staged GEMMs: head z (64) + w1 h (22) + roots (256) = 342 blocks
__global__ __launch_bounds__(256, 3) void k_mm1(
    const float* __restrict__ x, const float* __restrict__ headW,
    const float* __restrict__ w10, const float* __restrict__ w11,
    const float* __restrict__ w12,
    float* zA, float* zB,
    float* h0a, float* h0b, float* h1a, float* h1b, float* h2a, float* h2b,
    float* __restrict__ rootlogit)
{
    __shared__ __align__(16) short smem[64 * 12 * 32];  // 49 KB
    const int bx = blockIdx.x;
    if (bx < 64) {
        const int stripe = bx >> 1, kq = bx & 1;
        core_s<12, 0, 1>(x, INF, kq * 384, headW, INF, NHEAD, stripe, smem,
                         kq ? zB : zA, 2048, nullptr, 0, nullptr, 0);
    } else if (bx < 76) {
        const int m = bx - 64, stripe = m >> 1, kq = m & 1;
        core_s<12, 0, 1>(x, INF, kq * 384, w10, INF, 384, stripe, smem,
                         kq ? h0b : h0a, 384, nullptr, 0, nullptr, 0);
    } else if (bx < 82) {
        const int m = bx - 76, stripe = m >> 1, kq = m & 1;
        core_s<12, 0, 1>(x, INF, kq * 384, w11, INF, 192, stripe, smem,
                         kq ? h1b : h1a, 192, nullptr, 0, nullptr, 0);
    } else if (bx < 86) {
        const int m = bx - 82, stripe = m >> 1, kq = m & 1;
        core_s<12, 0, 1>(x, INF, kq * 384, w12, INF, 96, stripe, smem,
                         kq ? h2b : h2a, 96, nullptr, 0, nullptr, 0);
    } else {
        // exact fp32 root logits
        const int row = bx - 86, wave = threadIdx.x >> 6, lane = threadIdx.x & 63;
        if (wave < 3) {
            const float* xr = x + row * INF;
            const float* wr = headW + (size_t)(NSHORT + wave) * INF;
            float s = 0.f;
            for (int k = lane; k < INF; k += 64) s += xr[k] * wr[k];
            s = wreduce64(s);
            if (lane == 0) rootlogit[row * 3 + wave] = s;
        }
    }
}

// ln (192 blocks) + head softplus row-sums (256 blocks)
__global__ __launch_bounds__(256) void k_ln(const float* h0a, const float* h0b,
                                            const float* h1a, const float* h1b,
                                            const float* h2a, const float* h2b,
                                            const float* g0, const float* g1, const float* g2,
                                            const float* b0, const float* b1, const float* b2,
                                            const float* zA, const float* zB,
                                            __hip_bfloat16* f0, __hip_bfloat16* f1,
                                            __hip_bfloat16* f2,
                                            __hip_bfloat16* p0, __hip_bfloat16* p1,
                                            __hip_bfloat16* p2,
                                            float* __restrict__ phead) {
    const int bx = blockIdx.x;
    if (bx < 192) {
        const int task = bx * 4 + (threadIdx.x >> 6);  // 0..767
        const int ci = task >> 8, row = task & 255, lane = threadIdx.x & 63;
        const float *ha, *hb, *g, *bb; __hip_bfloat16 *fo, *po; int hsz, K32;
        if (ci == 0)      { ha = h0a; hb = h0b; g = g0; bb = b0; fo = f0; po = p0; hsz = 384; K32 = 12; }
        else if (ci == 1) { ha = h1a; hb = h1b; g = g1; bb = b1; fo = f1; po = p1; hsz = 192; K32 = 6; }
        else              { ha = h2a; hb = h2b; g = g2; bb = b2; fo = f2; po = p2; hsz = 96;  K32 = 3; }
        const float* hra = ha + row * hsz;
        const float* hrb = hb + row * hsz;
        float s = 0.f, s2 = 0.f;
        for (int k = lane; k < hsz; k += 64) {
            const float v = hra[k] + hrb[k]; s += v; s2 += v * v;
        }
        s = wreduce64(s); s2 = wreduce64(s2);
        const float mu = s / hsz;
        const float var = s2 / hsz - mu * mu;
        const float rsn = rsqrtf(var + 1e-5f);
        const int nch = hsz >> 3;
        if (lane < nch) {
            const f32x8 va = *(const f32x8*)(hra + lane * 8);
            const f32x8 vb = *(const f32x8*)(hrb + lane * 8);
            const f32x8 gg = *(const f32x8*)(g + lane * 8);
            const f32x8 bv = *(const f32x8*)(bb + lane * 8);
            s16x8 o;
#pragma unroll
            for (int i = 0; i < 8; i++)
                o[i] = bfc(fmaxf((va[i] + vb[i] - mu) * rsn * gg[i] + bv[i], 0.f));
            *(s16x8*)((short*)fo + (size_t)row * hsz + lane * 8) = o;
            const size_t chunk = ((size_t)(row >> 4) * K32 + (lane >> 2)) * 64
                               + (lane & 3) * 16 + (row & 15);
            *(s16x8*)((short*)po + chunk * 8) = o;
        }
    } else {
        // head softplus: sum_{col<2000} softplus(zA+zB); grouped log
        const int row = bx - 192, t = threadIdx.x;
        const int wave = t >> 6, lane = t & 63;
        float val = 0.f;
        if (t < 250) {
            const f32x8 a = *(const f32x8*)(zA + (size_t)row * 2048 + t * 8);
            const f32x8 b = *(const f32x8*)(zB + (size_t)row * 2048 + t * 8);
            float m = 0.f, P = 1.f;
#pragma unroll
            for (int i = 0; i < 8; i++) {
                const float z = a[i] + b[i];
                m += fmaxf(z, 0.f);
                P *= 1.f + __expf(-fabsf(z));
            }
            val = m + __logf(P);
        }
        val = wreduce64(val);
        __shared__ float red[4];
        if (lane == 0) red[wave] = val;
        __syncthreads();
        if (t == 0) phead[row] = red[0] + red[1] + red[2] + red[3];
    }
}

// BCE dense partials: 1533 stripe blocks, fp32 W staged in-kernel
__global__ __launch_bounds__(256, 3) void k_bce(const __hip_bfloat16* p0,
                                                const __hip_bfloat16* p1,
                                                const __hip_bfloat16* p2,
                                                const float* __restrict__ w20,
                                                const float* __restrict__ w21,
                                                const float* __restrict__ w22,
                                                float* __restrict__ part,
                                                const float* __restrict__ rootlogit) {
    __shared__ __align__(16) short smem[64 * 12 * 32];  // 49 KB (c0 worst case)
    const int s = blockIdx.x;
    if (s < 157)
        core_s<12, 2, 0>(p0, 12, 0, w20, 384, 10000, s, smem,
                         nullptr, 0, part, s, rootlogit, 0);
    else if (s < 595)
        core_s<6, 2, 0>(p1, 6, 0, w21, 192, 28000, s - 157, smem,
                        nullptr, 0, part, s, rootlogit, 1);
    else
        core_s<3, 2, 0>(p2, 3, 0, w22, 96, 60000, s - 595, smem,
                        nullptr, 0, part, s, rootlogit, 2);
}

// per-row: target corrections + partial reduction + final mean
__global__ __launch_bounds__(256) void k_red(const float* __restrict__ part,
                                             const float* __restrict__ phead,
                                             const float* __restrict__ rootlogit,
                                             const int* __restrict__ target,
                                             const float* __restrict__ x,
                                             const float* __restrict__ headW,
                                             const __hip_bfloat16* f0,
                                             const __hip_bfloat16* f1,
                                             const __hip_bfloat16* f2,
                                             const float* w20, const float* w21, const float* w22,
                                             float* __restrict__ out) {
    const int row = blockIdx.x;
    const int t = threadIdx.x, wave = t >> 6, lane = t & 63;
    __shared__ float sx[INF];
    __shared__ __hip_bfloat16 shb[384 + 192 + 96];
    __shared__ int st[20];
    __shared__ float scorr[4];
    __shared__ float red[4][4];
    for (int i = t; i < INF; i += 256) sx[i] = x[row * INF + i];
    for (int i = t; i < 384; i += 256) shb[i] = f0[row * 384 + i];
    for (int i = t; i < 192; i += 256) shb[384 + i] = f1[row * 192 + i];
    for (int i = t; i < 96; i += 256)  shb[576 + i] = f2[row * 96 + i];
    if (t < 20) st[t] = target[row * 20 + t];
    if (t < 4) scorr[t] = 0.f;
    __syncthreads();
    for (int l = wave; l < 20; l += 4) {
        const int tg = st[l];
        bool dup = false;
        for (int m = 0; m < l; m++) dup |= (st[m] == tg);
        if (dup) continue;
        if (tg < NSHORT) {
            const float* wr = headW + (size_t)tg * INF;
            float z = 0.f;
            for (int k = lane; k < INF; k += 64) z += sx[k] * wr[k];
            z = wreduce64(z);
            if (lane == 0) atomicAdd(&scorr[3], -z);
        } else {
            int ci, low, hsz, hoff; const float* w2;
            if (tg < 12000)      { ci = 0; low = 2000;  hsz = 384; hoff = 0;   w2 = w20; }
            else if (tg < 40000) { ci = 1; low = 12000; hsz = 192; hoff = 384; w2 = w21; }
            else                 { ci = 2; low = 40000; hsz = 96;  hoff = 576; w2 = w22; }
            const float* wr = w2 + (size_t)(tg - low) * hsz;
            float z = 0.f;
            for (int k = lane; k < hsz; k += 64)
                z += __bfloat162float(shb[hoff + k]) * wr[k];
            z = wreduce64(z);
            if (lane == 0) {
                const float rvv = sigf(rootlogit[row * 3 + ci]);
                const float p = rvv * sigf(z);
                atomicAdd(&scorr[ci],
                          -fmaxf(__logf(p), -100.f) + fmaxf(__logf(1.f - p), -100.f));
            }
        }
    }
    // dense-partial reduction
    float c0 = 0.f, c1 = 0.f, c2 = 0.f;
    for (int i = t; i < 1533; i += 256) {
        const float v = part[(size_t)i * 256 + row];
        if (i < 157) c0 += v; else if (i < 595) c1 += v; else c2 += v;
    }
    c0 = wreduce64(c0); c1 = wreduce64(c1); c2 = wreduce64(c2);
    if (lane == 0) { red[0][wave] = c0; red[1][wave] = c1; red[2][wave] = c2; }
    __syncthreads();
    if (t == 0) {
        float cc[3];
        for (int i = 0; i < 3; i++) cc[i] = red[i][0] + red[i][1] + red[i][2] + red[i][3];
        float hsum = phead[row] + scorr[3];
        bool act[3] = {false, false, false};
        for (int l = 0; l < 20; l++) {
            const int tg = target[row * 20 + l];
            if (tg >= 2000) {
                if (tg < 12000) act[0] = true;
                else if (tg < 40000) act[1] = true;
                else act[2] = true;
            }
        }
        float total = 0.f, num = 2000.f;
        const float csz[3] = {10000.f, 28000.f, 60000.f};
        for (int i = 0; i < 3; i++) {
            if (act[i]) { total += cc[i] + scorr[i]; num += csz[i]; }
            else        { hsum += softplusf(rootlogit[row * 3 + i]); num += 1.f; }
        }
        atomicAdd(out, (hsum + total) / num * (1.f / 256.f));
    }
}

extern "C" void kernel_launch(void* const* d_in, const int* in_sizes, int n_in,
                              void* d_out, int out_size, void* d_ws, size_t ws_size,
                              hipStream_t stream) {
    const float* x      = (const float*)d_in[0];
    const float* headW  = (const float*)d_in[1];
    const int*   target = (const int*)d_in[2];
    const float* w10 = (const float*)d_in[3];
    const float* g0  = (const float*)d_in[4];
    const float* b0  = (const float*)d_in[5];
    const float* w20 = (const float*)d_in[6];
    const float* w11 = (const float*)d_in[7];
    const float* g1  = (const float*)d_in[8];
    const float* b1  = (const float*)d_in[9];
    const float* w21 = (const float*)d_in[10];
    const float* w12 = (const float*)d_in[11];
    const float* g2  = (const float*)d_in[12];
    const float* b2  = (const float*)d_in[13];
    const float* w22 = (const float*)d_in[14];
    float* out = (float*)d_out;

    char* ws = (char*)d_ws;
    size_t off = 0;
    auto carve = [&](size_t bytes) -> void* {
        void* p = ws + off;
        off += (bytes + 255) & ~(size_t)255;
        return p;
    };
    float* zA            = (float*)carve((size_t)256 * 2048 * 4);
    float* zB            = (float*)carve((size_t)256 * 2048 * 4);
    float* h0a           = (float*)carve((size_t)256 * 384 * 4);
    float* h0b           = (float*)carve((size_t)256 * 384 * 4);
    float* h1a           = (float*)carve((size_t)256 * 192 * 4);
    float* h1b           = (float*)carve((size_t)256 * 192 * 4);
    float* h2a           = (float*)carve((size_t)256 * 96 * 4);
    float* h2b           = (float*)carve((size_t)256 * 96 * 4);
    __hip_bfloat16* f0   = (__hip_bfloat16*)carve((size_t)256 * 384 * 2);
    __hip_bfloat16* f1   = (__hip_bfloat16*)carve((size_t)256 * 192 * 2);
    __hip_bfloat16* f2   = (__hip_bfloat16*)carve((size_t)256 * 96 * 2);
    __hip_bfloat16* p0   = (__hip_bfloat16*)carve((size_t)256 * 384 * 2);
    __hip_bfloat16* p1   = (__hip_bfloat16*)carve((size_t)256 * 192 * 2);
    __hip_bfloat16* p2   = (__hip_bfloat16*)carve((size_t)256 * 96 * 2);
    float* rootlogit     = (float*)carve((size_t)256 * 3 * 4);
    float* phead         = (float*)carve((size_t)256 * 4);
    float* part          = (float*)carve((size_t)1536 * 256 * 4);

    hipMemsetAsync(out, 0, sizeof(float), stream);

    k_mm1<<<342, 256, 0, stream>>>(x, headW, w10, w11, w12,
                                   zA, zB, h0a, h0b, h1a, h1b, h2a, h2b, rootlogit);
    k_ln<<<448, 256, 0, stream>>>(h0a, h0b, h1a, h1b, h2a, h2b,
                                  g0, g1, g2, b0, b1, b2, zA, zB,
                                  f0, f1, f2, p0, p1, p2, phead);
    k_bce<<<1533, 256, 0, stream>>>(p0, p1, p2, w20, w21, w22, part, rootlogit);
    k_red<<<256, 256, 0, stream>>>(part, phead, rootlogit, target, x, headW,
                                   f0, f1, f2, w20, w21, w22, out);

    (void)in_sizes; (void)n_in; (void)out_size; (void)ws_size;
}

// Round 8
// 182.349 us; speedup vs baseline: 1.0280x; 1.0280x over previous
//
#include <hip/hip_runtime.h>
#include <hip/hip_bf16.h>

#define INF 768
#define NSHORT 2000
#define NHEAD 2003

typedef __attribute__((ext_vector_type(8))) short  s16x8;
typedef __attribute__((ext_vector_type(4))) float  f32x4;
typedef __attribute__((ext_vector_type(8))) float  f32x8;

__device__ __forceinline__ float sigf(float z) { return 1.f / (1.f + __expf(-z)); }
__device__ __forceinline__ float softplusf(float z) {
    return fmaxf(z, 0.f) + __logf(1.f + __expf(-fabsf(z)));
}
__device__ __forceinline__ float qreduce16(float v) {
    v += __shfl_xor(v, 1); v += __shfl_xor(v, 2);
    v += __shfl_xor(v, 4); v += __shfl_xor(v, 8);
    return v;
}
__device__ __forceinline__ float wreduce64(float v) {
    v += __shfl_xor(v, 1);  v += __shfl_xor(v, 2);  v += __shfl_xor(v, 4);
    v += __shfl_xor(v, 8);  v += __shfl_xor(v, 16); v += __shfl_xor(v, 32);
    return v;
}
__device__ __forceinline__ short bfc(float x) {
    union { __hip_bfloat16 h; short s; } u; u.h = __float2bfloat16(x); return u.s;
}

// ---- chunked double-buffered staged MFMA GEMM ----
// Block = 256 rows x 64-col stripe, 4 waves x 64 rows. K split into NCH=K32/KC chunks.
// Per chunk: issue next chunk's W loads -> MFMA current (LDS) -> cvt+write next -> barrier.
// W fragment in LDS: ((jj*4+ct)*64+lane)*8 shorts. A: AF32? fp32 rows (cvt in-loop)
// : fragment-linear bf16 (chunk=(rtile*K32+jg)*64+lane).
// MODE 0: store z (col<N). MODE 2: grouped-log BCE row-sums -> part[pslot*256+row].
template <int K32, int KC, int MODE, int AF32>
__device__ __forceinline__ void core_c(
    const void* __restrict__ Av, int kbase32,
    const float* __restrict__ W, int Kfull, int N, int stripe,
    short* __restrict__ lds,
    float* __restrict__ outH, int ldH,
    float* __restrict__ part, int pslot,
    const float* __restrict__ rootlogit, int ci)
{
    constexpr int NCH = K32 / KC;
    const int t = threadIdx.x;
    const int wave = t >> 6, lane = t & 63;
    const int quad = lane >> 4, l16 = lane & 15;
    const int rtb = wave * 4;

    // staging role: thread t = (ct = t>>6, l = t&63)
    const int sct = t >> 6, sl = t & 63;
    int scol = stripe * 64 + sct * 16 + (sl & 15);
    if (scol >= N) scol = N - 1;
    const float* wsrc = W + (size_t)scol * Kfull + kbase32 * 32 + (sl >> 4) * 8;

    // A element offsets
    size_t aoff[4];
#pragma unroll
    for (int rt = 0; rt < 4; rt++) {
        if (AF32)
            aoff[rt] = (size_t)((rtb + rt) * 16 + l16) * Kfull + kbase32 * 32 + quad * 8;
        else
            aoff[rt] = (size_t)(rtb + rt) * K32 * 512 + (size_t)lane * 8;
    }

    // stage chunk 0
#pragma unroll
    for (int s = 0; s < KC; s++) {
        const f32x8 v = *(const f32x8*)(wsrc + (size_t)s * 32);
        s16x8 o;
#pragma unroll
        for (int i = 0; i < 8; i++) o[i] = bfc(v[i]);
        *(s16x8*)(lds + (((size_t)s * 4 + sct) * 64 + sl) * 8) = o;
    }
    __syncthreads();

    f32x4 acc[4][4];
#pragma unroll
    for (int rt = 0; rt < 4; rt++)
#pragma unroll
        for (int ct = 0; ct < 4; ct++) acc[rt][ct] = (f32x4){0.f, 0.f, 0.f, 0.f};

#pragma unroll
    for (int c = 0; c < NCH; c++) {
        short* lbuf = lds + (size_t)(c & 1) * (KC * 2048);
        f32x8 nv[KC];
        if (c + 1 < NCH) {   // issue next-chunk loads; they fly during MFMA below
#pragma unroll
            for (int s = 0; s < KC; s++)
                nv[s] = *(const f32x8*)(wsrc + ((size_t)((c + 1) * KC + s)) * 32);
        }
#pragma unroll
        for (int jj = 0; jj < KC; jj++) {
            const int jg = c * KC + jj;
            s16x8 af[4];
            if (AF32) {
#pragma unroll
                for (int rt = 0; rt < 4; rt++) {
                    const f32x8 v = *(const f32x8*)((const float*)Av + aoff[rt] + (size_t)jg * 32);
#pragma unroll
                    for (int i = 0; i < 8; i++) af[rt][i] = bfc(v[i]);
                }
            } else {
#pragma unroll
                for (int rt = 0; rt < 4; rt++)
                    af[rt] = *(const s16x8*)((const short*)Av + aoff[rt] + (size_t)jg * 512);
            }
#pragma unroll
            for (int ct = 0; ct < 4; ct++) {
                const s16x8 wf = *(const s16x8*)(lbuf + (((size_t)jj * 4 + ct) * 64 + lane) * 8);
#pragma unroll
                for (int rt = 0; rt < 4; rt++)
                    acc[rt][ct] = __builtin_amdgcn_mfma_f32_16x16x32_bf16(
                        af[rt], wf, acc[rt][ct], 0, 0, 0);
            }
        }
        if (c + 1 < NCH) {
            short* nbuf = lds + (size_t)((c + 1) & 1) * (KC * 2048);
#pragma unroll
            for (int s = 0; s < KC; s++) {
                s16x8 o;
#pragma unroll
                for (int i = 0; i < 8; i++) o[i] = bfc(nv[s][i]);
                *(s16x8*)(nbuf + (((size_t)s * 4 + sct) * 64 + sl) * 8) = o;
            }
            __syncthreads();
        }
    }

    const int col0 = stripe * 64;
    if (MODE == 0) {
#pragma unroll
        for (int rt = 0; rt < 4; rt++)
#pragma unroll
            for (int ct = 0; ct < 4; ct++) {
                const int col = col0 + ct * 16 + l16;
                if (col < N) {
#pragma unroll
                    for (int r = 0; r < 4; r++)
                        outH[(size_t)((rtb + rt) * 16 + quad * 4 + r) * ldH + col] =
                            acc[rt][ct][r];
                }
            }
    } else {
        // sum_ct -log(1-r*sig(z)) = log prod(1+t) - log prod(1+t-r), t=e^-z
#pragma unroll
        for (int rt = 0; rt < 4; rt++) {
#pragma unroll
            for (int r = 0; r < 4; r++) {
                const int row = (rtb + rt) * 16 + quad * 4 + r;
                const float rv = sigf(rootlogit[row * 3 + ci]);
                float pd = 1.f, pn = 1.f;
#pragma unroll
                for (int ct = 0; ct < 4; ct++) {
                    const int col = col0 + ct * 16 + l16;
                    const float tv = fminf(__expf(-acc[rt][ct][r]), 1e6f);
                    const float d = (col < N) ? (1.f + tv) : 1.f;
                    const float n = (col < N) ? (1.f + tv - rv) : 1.f;
                    pd *= d; pn *= n;
                }
                float s = __logf(pd) - __logf(pn);
                s = qreduce16(s);
                if (l16 == 0) part[(size_t)pslot * 256 + row] = s;
            }
        }
    }
}

// split-K(x4) staged GEMMs: head z (128) + w1 h (44) + roots (256) = 428 blocks
__global__ __launch_bounds__(256, 2) void k_mm1(
    const float* __restrict__ x, const float* __restrict__ headW,
    const float* __restrict__ w10, const float* __restrict__ w11,
    const float* __restrict__ w12,
    float* __restrict__ zbase,               // [4][256][2048]
    float* __restrict__ h0base,              // [4][256][384]
    float* __restrict__ h1base,              // [4][256][192]
    float* __restrict__ h2base,              // [4][256][96]
    float* __restrict__ rootlogit)
{
    __shared__ __align__(16) short smem[8192];  // 16 KB (2 x KC=2 chunks)
    const int bx = blockIdx.x;
    if (bx < 128) {
        const int stripe = bx >> 2, kq = bx & 3;
        core_c<6, 2, 0, 1>(x, kq * 6, headW, INF, NHEAD, stripe, smem,
                           zbase + (size_t)kq * 256 * 2048, 2048,
                           nullptr, 0, nullptr, 0);
    } else if (bx < 172) {
        const int m = bx - 128;
        if (m < 24) {
            const int stripe = m >> 2, kq = m & 3;
            core_c<6, 2, 0, 1>(x, kq * 6, w10, INF, 384, stripe, smem,
                               h0base + (size_t)kq * 256 * 384, 384,
                               nullptr, 0, nullptr, 0);
        } else if (m < 36) {
            const int m2 = m - 24, stripe = m2 >> 2, kq = m2 & 3;
            core_c<6, 2, 0, 1>(x, kq * 6, w11, INF, 192, stripe, smem,
                               h1base + (size_t)kq * 256 * 192, 192,
                               nullptr, 0, nullptr, 0);
        } else {
            const int m2 = m - 36, stripe = m2 >> 2, kq = m2 & 3;
            core_c<6, 2, 0, 1>(x, kq * 6, w12, INF, 96, stripe, smem,
                               h2base + (size_t)kq * 256 * 96, 96,
                               nullptr, 0, nullptr, 0);
        }
    } else {
        // exact fp32 root logits
        const int row = bx - 172, wave = threadIdx.x >> 6, lane = threadIdx.x & 63;
        if (wave < 3) {
            const float* xr = x + row * INF;
            const float* wr = headW + (size_t)(NSHORT + wave) * INF;
            float s = 0.f;
            for (int k = lane; k < INF; k += 64) s += xr[k] * wr[k];
            s = wreduce64(s);
            if (lane == 0) rootlogit[row * 3 + wave] = s;
        }
    }
}

// ln (192 blocks) + head softplus row-sums (256 blocks); also zeroes out[0]
__global__ __launch_bounds__(256) void k_ln(const float* __restrict__ h0base,
                                            const float* __restrict__ h1base,
                                            const float* __restrict__ h2base,
                                            const float* g0, const float* g1, const float* g2,
                                            const float* b0, const float* b1, const float* b2,
                                            const float* __restrict__ zbase,
                                            __hip_bfloat16* f0, __hip_bfloat16* f1,
                                            __hip_bfloat16* f2,
                                            __hip_bfloat16* p0, __hip_bfloat16* p1,
                                            __hip_bfloat16* p2,
                                            float* __restrict__ phead,
                                            float* __restrict__ out) {
    const int bx = blockIdx.x;
    if (bx == 0 && threadIdx.x == 0) out[0] = 0.f;  // runs before k_red
    if (bx < 192) {
        const int task = bx * 4 + (threadIdx.x >> 6);  // 0..767
        const int ci = task >> 8, row = task & 255, lane = threadIdx.x & 63;
        const float *hb, *g, *bb; __hip_bfloat16 *fo, *po; int hsz, K32;
        if (ci == 0)      { hb = h0base; g = g0; bb = b0; fo = f0; po = p0; hsz = 384; K32 = 12; }
        else if (ci == 1) { hb = h1base; g = g1; bb = b1; fo = f1; po = p1; hsz = 192; K32 = 6; }
        else              { hb = h2base; g = g2; bb = b2; fo = f2; po = p2; hsz = 96;  K32 = 3; }
        const size_t qs = (size_t)256 * hsz;
        const float* hr = hb + (size_t)row * hsz;
        float s = 0.f, s2 = 0.f;
        for (int k = lane; k < hsz; k += 64) {
            const float v = hr[k] + hr[qs + k] + hr[2 * qs + k] + hr[3 * qs + k];
            s += v; s2 += v * v;
        }
        s = wreduce64(s); s2 = wreduce64(s2);
        const float mu = s / hsz;
        const float var = s2 / hsz - mu * mu;
        const float rsn = rsqrtf(var + 1e-5f);
        const int nch = hsz >> 3;
        if (lane < nch) {
            f32x8 v = *(const f32x8*)(hr + lane * 8);
            const f32x8 v1 = *(const f32x8*)(hr + qs + lane * 8);
            const f32x8 v2 = *(const f32x8*)(hr + 2 * qs + lane * 8);
            const f32x8 v3 = *(const f32x8*)(hr + 3 * qs + lane * 8);
            const f32x8 gg = *(const f32x8*)(g + lane * 8);
            const f32x8 bv = *(const f32x8*)(bb + lane * 8);
            s16x8 o;
#pragma unroll
            for (int i = 0; i < 8; i++) {
                const float hv = v[i] + v1[i] + v2[i] + v3[i];
                o[i] = bfc(fmaxf((hv - mu) * rsn * gg[i] + bv[i], 0.f));
            }
            *(s16x8*)((short*)fo + (size_t)row * hsz + lane * 8) = o;
            const size_t chunk = ((size_t)(row >> 4) * K32 + (lane >> 2)) * 64
                               + (lane & 3) * 16 + (row & 15);
            *(s16x8*)((short*)po + chunk * 8) = o;
        }
    } else {
        // head softplus: sum_{col<2000} softplus(sum_q z_q); grouped log
        const int row = bx - 192, t = threadIdx.x;
        const int wave = t >> 6, lane = t & 63;
        float val = 0.f;
        if (t < 250) {
            const size_t base = (size_t)row * 2048 + t * 8;
            const f32x8 a = *(const f32x8*)(zbase + base);
            const f32x8 b = *(const f32x8*)(zbase + 524288 + base);
            const f32x8 c = *(const f32x8*)(zbase + 2 * 524288 + base);
            const f32x8 d = *(const f32x8*)(zbase + 3 * 524288 + base);
            float m = 0.f, P = 1.f;
#pragma unroll
            for (int i = 0; i < 8; i++) {
                const float z = a[i] + b[i] + c[i] + d[i];
                m += fmaxf(z, 0.f);
                P *= 1.f + __expf(-fabsf(z));
            }
            val = m + __logf(P);
        }
        val = wreduce64(val);
        __shared__ float red[4];
        if (lane == 0) red[wave] = val;
        __syncthreads();
        if (t == 0) phead[row] = red[0] + red[1] + red[2] + red[3];
    }
}

// BCE dense partials: 1533 stripe blocks, chunked dbuf staging
__global__ __launch_bounds__(256, 4) void k_bce(const __hip_bfloat16* p0,
                                                const __hip_bfloat16* p1,
                                                const __hip_bfloat16* p2,
                                                const float* __restrict__ w20,
                                                const float* __restrict__ w21,
                                                const float* __restrict__ w22,
                                                float* __restrict__ part,
                                                const float* __restrict__ rootlogit) {
    __shared__ __align__(16) short smem[8192];  // 16 KB
    const int s = blockIdx.x;
    if (s < 157)
        core_c<12, 2, 2, 0>(p0, 0, w20, 384, 10000, s, smem,
                            nullptr, 0, part, s, rootlogit, 0);
    else if (s < 595)
        core_c<6, 2, 2, 0>(p1, 0, w21, 192, 28000, s - 157, smem,
                           nullptr, 0, part, s, rootlogit, 1);
    else
        core_c<3, 3, 2, 0>(p2, 0, w22, 96, 60000, s - 595, smem,
                           nullptr, 0, part, s, rootlogit, 2);
}

// per-row: target corrections + partial reduction + final mean
__global__ __launch_bounds__(256) void k_red(const float* __restrict__ part,
                                             const float* __restrict__ phead,
                                             const float* __restrict__ rootlogit,
                                             const int* __restrict__ target,
                                             const float* __restrict__ x,
                                             const float* __restrict__ headW,
                                             const __hip_bfloat16* f0,
                                             const __hip_bfloat16* f1,
                                             const __hip_bfloat16* f2,
                                             const float* w20, const float* w21, const float* w22,
                                             float* __restrict__ out) {
    const int row = blockIdx.x;
    const int t = threadIdx.x, wave = t >> 6, lane = t & 63;
    __shared__ float sx[INF];
    __shared__ __hip_bfloat16 shb[384 + 192 + 96];
    __shared__ int st[20];
    __shared__ float scorr[4];
    __shared__ float red[4][4];
    for (int i = t; i < INF; i += 256) sx[i] = x[row * INF + i];
    for (int i = t; i < 384; i += 256) shb[i] = f0[row * 384 + i];
    for (int i = t; i < 192; i += 256) shb[384 + i] = f1[row * 192 + i];
    for (int i = t; i < 96; i += 256)  shb[576 + i] = f2[row * 96 + i];
    if (t < 20) st[t] = target[row * 20 + t];
    if (t < 4) scorr[t] = 0.f;
    __syncthreads();
    for (int l = wave; l < 20; l += 4) {
        const int tg = st[l];
        bool dup = false;
        for (int m = 0; m < l; m++) dup |= (st[m] == tg);
        if (dup) continue;
        if (tg < NSHORT) {
            const float* wr = headW + (size_t)tg * INF;
            float z = 0.f;
            for (int k = lane; k < INF; k += 64) z += sx[k] * wr[k];
            z = wreduce64(z);
            if (lane == 0) atomicAdd(&scorr[3], -z);
        } else {
            int ci, low, hsz, hoff; const float* w2;
            if (tg < 12000)      { ci = 0; low = 2000;  hsz = 384; hoff = 0;   w2 = w20; }
            else if (tg < 40000) { ci = 1; low = 12000; hsz = 192; hoff = 384; w2 = w21; }
            else                 { ci = 2; low = 40000; hsz = 96;  hoff = 576; w2 = w22; }
            const float* wr = w2 + (size_t)(tg - low) * hsz;
            float z = 0.f;
            for (int k = lane; k < hsz; k += 64)
                z += __bfloat162float(shb[hoff + k]) * wr[k];
            z = wreduce64(z);
            if (lane == 0) {
                const float rvv = sigf(rootlogit[row * 3 + ci]);
                const float p = rvv * sigf(z);
                atomicAdd(&scorr[ci],
                          -fmaxf(__logf(p), -100.f) + fmaxf(__logf(1.f - p), -100.f));
            }
        }
    }
    // dense-partial reduction
    float c0 = 0.f, c1 = 0.f, c2 = 0.f;
    for (int i = t; i < 1533; i += 256) {
        const float v = part[(size_t)i * 256 + row];
        if (i < 157) c0 += v; else if (i < 595) c1 += v; else c2 += v;
    }
    c0 = wreduce64(c0); c1 = wreduce64(c1); c2 = wreduce64(c2);
    if (lane == 0) { red[0][wave] = c0; red[1][wave] = c1; red[2][wave] = c2; }
    __syncthreads();
    if (t == 0) {
        float cc[3];
        for (int i = 0; i < 3; i++) cc[i] = red[i][0] + red[i][1] + red[i][2] + red[i][3];
        float hsum = phead[row] + scorr[3];
        bool act[3] = {false, false, false};
        for (int l = 0; l < 20; l++) {
            const int tg = target[row * 20 + l];
            if (tg >= 2000) {
                if (tg < 12000) act[0] = true;
                else if (tg < 40000) act[1] = true;
                else act[2] = true;
            }
        }
        float total = 0.f, num = 2000.f;
        const float csz[3] = {10000.f, 28000.f, 60000.f};
        for (int i = 0; i < 3; i++) {
            if (act[i]) { total += cc[i] + scorr[i]; num += csz[i]; }
            else        { hsum += softplusf(rootlogit[row * 3 + i]); num += 1.f; }
        }
        atomicAdd(out, (hsum + total) / num * (1.f / 256.f));
    }
}

extern "C" void kernel_launch(void* const* d_in, const int* in_sizes, int n_in,
                              void* d_out, int out_size, void* d_ws, size_t ws_size,
                              hipStream_t stream) {
    const float* x      = (const float*)d_in[0];
    const float* headW  = (const float*)d_in[1];
    const int*   target = (const int*)d_in[2];
    const float* w10 = (const float*)d_in[3];
    const float* g0  = (const float*)d_in[4];
    const float* b0  = (const float*)d_in[5];
    const float* w20 = (const float*)d_in[6];
    const float* w11 = (const float*)d_in[7];
    const float* g1  = (const float*)d_in[8];
    const float* b1  = (const float*)d_in[9];
    const float* w21 = (const float*)d_in[10];
    const float* w12 = (const float*)d_in[11];
    const float* g2  = (const float*)d_in[12];
    const float* b2  = (const float*)d_in[13];
    const float* w22 = (const float*)d_in[14];
    float* out = (float*)d_out;

    char* ws = (char*)d_ws;
    size_t off = 0;
    auto carve = [&](size_t bytes) -> void* {
        void* p = ws + off;
        off += (bytes + 255) & ~(size_t)255;
        return p;
    };
    float* zbase         = (float*)carve((size_t)4 * 256 * 2048 * 4);
    float* h0base        = (float*)carve((size_t)4 * 256 * 384 * 4);
    float* h1base        = (float*)carve((size_t)4 * 256 * 192 * 4);
    float* h2base        = (float*)carve((size_t)4 * 256 * 96 * 4);
    __hip_bfloat16* f0   = (__hip_bfloat16*)carve((size_t)256 * 384 * 2);
    __hip_bfloat16* f1   = (__hip_bfloat16*)carve((size_t)256 * 192 * 2);
    __hip_bfloat16* f2   = (__hip_bfloat16*)carve((size_t)256 * 96 * 2);
    __hip_bfloat16* p0   = (__hip_bfloat16*)carve((size_t)256 * 384 * 2);
    __hip_bfloat16* p1   = (__hip_bfloat16*)carve((size_t)256 * 192 * 2);
    __hip_bfloat16* p2   = (__hip_bfloat16*)carve((size_t)256 * 96 * 2);
    float* rootlogit     = (float*)carve((size_t)256 * 3 * 4);
    float* phead         = (float*)carve((size_t)256 * 4);
    float* part          = (float*)carve((size_t)1536 * 256 * 4);

    k_mm1<<<428, 256, 0, stream>>>(x, headW, w10, w11, w12,
                                   zbase, h0base, h1base, h2base, rootlogit);
    k_ln<<<448, 256, 0, stream>>>(h0base, h1base, h2base,
                                  g0, g1, g2, b0, b1, b2, zbase,
                                  f0, f1, f2, p0, p1, p2, phead, out);
    k_bce<<<1533, 256, 0, stream>>>(p0, p1, p2, w20, w21, w22, part, rootlogit);
    k_red<<<256, 256, 0, stream>>>(part, phead, rootlogit, target, x, headW,
                                   f0, f1, f2, w20, w21, w22, out);

    (void)in_sizes; (void)n_in; (void)out_size; (void)ws_size;
}